// Round 6
// baseline (341.817 us; speedup 1.0000x reference)
//
#include <hip/hip_runtime.h>
#include <math.h>

#define B_   4
#define N_   4096
#define D_   1024
#define DFF_ 4096
#define K_   2048

typedef __attribute__((ext_vector_type(8))) short short8;
typedef __attribute__((ext_vector_type(4))) float float4v;

__device__ __forceinline__ unsigned short f2bf(float f) {
    unsigned int u = __float_as_uint(f);
    u = (u + 0x7fffu + ((u >> 16) & 1u)) >> 16;   // RNE
    return (unsigned short)u;
}

__device__ __forceinline__ void gld16(const void* g, void* l) {
    __builtin_amdgcn_global_load_lds((const __attribute__((address_space(1))) void*)g,
                                     (__attribute__((address_space(3))) void*)l, 16, 0, 0);
}

// ---------------- scores (bit-identical selection math) + slot clear ----------------
__global__ __launch_bounds__(256) void scores_kernel(const float* __restrict__ x,
                                                     const float* __restrict__ gate_w,
                                                     float* __restrict__ scores,
                                                     int* __restrict__ slot) {
    int wave = (blockIdx.x * blockDim.x + threadIdx.x) >> 6;
    int lane = threadIdx.x & 63;
    if (wave >= B_ * N_) return;
    if (lane == 1) slot[wave] = -1;
    const float4* xr = (const float4*)(x + (size_t)wave * D_);
    const float4* g  = (const float4*)gate_w;
    float acc = 0.f;
    #pragma unroll
    for (int j = 0; j < D_ / 4 / 64; ++j) {
        float4 a = xr[lane + j * 64];
        float4 b = g[lane + j * 64];
        acc += a.x * b.x + a.y * b.y + a.z * b.z + a.w * b.w;
    }
    #pragma unroll
    for (int off = 32; off > 0; off >>= 1) acc += __shfl_down(acc, off, 64);
    if (lane == 0) scores[wave] = acc;
}

// ---------------- top-k radix select, wave-level scans; writes topk + global slot map ----------------
__global__ __launch_bounds__(1024) void select_topk_kernel(const float* __restrict__ scores,
                                                           int* __restrict__ topk,
                                                           int* __restrict__ slot) {
    __shared__ unsigned key[N_];
    __shared__ unsigned hist[256];
    __shared__ int sh_bin, sh_rem, sh_ngt;
    __shared__ int wsum[16], woff[16];
    int b = blockIdx.x, tid = threadIdx.x;
    int lane = tid & 63, wid = tid >> 6;

    for (int i = tid; i < N_; i += 1024) {
        unsigned u = __float_as_uint(scores[b * N_ + i]);
        key[i] = (u & 0x80000000u) ? ~u : (u | 0x80000000u);   // monotonic map
    }
    if (tid == 0) sh_ngt = 0;
    __syncthreads();

    unsigned prefix = 0, pmask = 0;
    int rem = K_;
    for (int shift = 24; shift >= 0; shift -= 8) {
        if (tid < 256) hist[tid] = 0;
        __syncthreads();
        for (int i = tid; i < N_; i += 1024) {
            unsigned k = key[i];
            if ((k & pmask) == prefix) atomicAdd(&hist[(k >> shift) & 255u], 1u);
        }
        __syncthreads();
        if (tid < 64) {   // wave 0: suffix scan of 256 bins, 4 bins/lane
            unsigned v0 = hist[4 * lane], v1 = hist[4 * lane + 1];
            unsigned v2 = hist[4 * lane + 2], v3 = hist[4 * lane + 3];
            unsigned s3 = v3, s2 = v2 + s3, s1 = v1 + s2, s0 = v0 + s1;
            unsigned t = s0;
            #pragma unroll
            for (int off = 1; off < 64; off <<= 1) {
                unsigned u = __shfl_down(t, off, 64);
                if (lane + off < 64) t += u;
            }
            unsigned above = t - s0;                  // keys in bins > 4*lane+3
            unsigned S0 = s0 + above, S1 = s1 + above, S2 = s2 + above, S3 = s3 + above;
            unsigned R = (unsigned)rem;
            if (S0 >= R && S1 < R) { sh_bin = 4 * lane;     sh_rem = rem - (int)S1; }
            if (S1 >= R && S2 < R) { sh_bin = 4 * lane + 1; sh_rem = rem - (int)S2; }
            if (S2 >= R && S3 < R) { sh_bin = 4 * lane + 2; sh_rem = rem - (int)S3; }
            if (S3 >= R && above < R) { sh_bin = 4 * lane + 3; sh_rem = rem - (int)above; }
        }
        __syncthreads();
        prefix |= ((unsigned)sh_bin) << shift;
        pmask  |= 0xffu << shift;
        rem = sh_rem;
    }
    unsigned T = prefix;          // exact key of k-th largest
    int c_gt = K_ - rem;          // count strictly greater

    // strictly-greater: ballot-compacted, arbitrary order, slots [0, c_gt)
    for (int i = tid; i < N_; i += 1024) {
        bool p = key[i] > T;
        unsigned long long m = __ballot(p);
        int cnt = __popcll(m);
        int basepos = 0;
        if (lane == 0 && cnt) basepos = atomicAdd(&sh_ngt, cnt);
        basepos = __shfl(basepos, 0, 64);
        if (p) {
            int pos = basepos + __popcll(m & ((1ULL << lane) - 1ULL));
            topk[b * K_ + pos] = i;
            slot[b * N_ + i] = b * K_ + pos;
        }
    }
    // ties: first `rem` by index -> slots [c_gt, K)
    int base = tid * 4, c = 0;
    #pragma unroll
    for (int j = 0; j < 4; ++j) c += (key[base + j] == T);
    int sc = c;
    #pragma unroll
    for (int off = 1; off < 64; off <<= 1) {
        int u = __shfl_up(sc, off, 64);
        if (lane >= off) sc += u;
    }
    if (lane == 63) wsum[wid] = sc;
    __syncthreads();
    if (tid == 0) {
        int run = 0;
        #pragma unroll
        for (int j = 0; j < 16; ++j) { woff[j] = run; run += wsum[j]; }
    }
    __syncthreads();
    int r = woff[wid] + sc - c;   // exclusive prefix among ties
    #pragma unroll
    for (int j = 0; j < 4; ++j) {
        if (key[base + j] == T) {
            if (r < rem) {
                topk[b * K_ + c_gt + r] = base + j;
                slot[b * N_ + base + j] = b * K_ + c_gt + r;
            }
            ++r;
        }
    }
}

// ---------------- fused: selected rows -> bf16 xsel[slot]; unselected -> out copy ----------------
__global__ __launch_bounds__(256) void gather_copy_kernel(const float* __restrict__ x,
                                                          const int* __restrict__ slot,
                                                          unsigned short* __restrict__ xsel,
                                                          float* __restrict__ out) {
    int row = blockIdx.x;
    int t = threadIdx.x;
    int s = slot[row];
    float4 v = ((const float4*)(x + (size_t)row * D_))[t];
    if (s >= 0) {
        ushort4 o;
        o.x = f2bf(v.x); o.y = f2bf(v.y); o.z = f2bf(v.z); o.w = f2bf(v.w);
        ((ushort4*)(xsel + (size_t)s * D_))[t] = o;
    } else {
        ((float4*)(out + (size_t)row * D_))[t] = v;
    }
}

// ---------------- both weight transposes (fp32 [R][C] -> bf16 [C][R]) in one launch ----------------
__global__ __launch_bounds__(256) void transpose_both_kernel(const float* __restrict__ w1,
                                                             const float* __restrict__ w2,
                                                             unsigned short* __restrict__ w1t,
                                                             unsigned short* __restrict__ w2t) {
    __shared__ float tile[32][33];
    int bid = blockIdx.x;
    const float* src; unsigned short* dst; int R, C, bx, by;
    if (bid < 4096) { src = w1; dst = w1t; R = D_;   C = DFF_; bx = bid & 127;          by = bid >> 7; }
    else            { src = w2; dst = w2t; R = DFF_; C = D_;   bx = (bid - 4096) & 31;  by = (bid - 4096) >> 5; }
    int tx = threadIdx.x & 31, ty = threadIdx.x >> 5;   // 32 x 8
    int c = bx * 32 + tx, r0 = by * 32;
    #pragma unroll
    for (int j = ty; j < 32; j += 8) tile[j][tx] = src[(size_t)(r0 + j) * C + c];
    __syncthreads();
    int dc = by * 32 + tx, dr0 = bx * 32;
    #pragma unroll
    for (int j = ty; j < 32; j += 8) dst[(size_t)(dr0 + j) * R + dc] = f2bf(tile[tx][j]);
}

// ======== row-pair XOR swizzle (verified r3: conflicts -> 0) ========
// Row = 32 shorts (4 x 16B chunks). Logical chunk (r, kc) stored at chunk index
// (r>>1)*8 + ((((r&1)<<2)|kc) ^ ((r>>1)&7)). LDS dest linear for global_load_lds;
// permutation applied to global source + ds_read address (same involution).

// ======== ring-4 counted-vmcnt pipeline (T3+T4) ========
// 128x128 tile, BK=32, 256 thr (4 waves 2Mx2N, 64x64/wave). Ring of 4 x 16 KiB
// buffers (64 KiB total -> 2 blocks/CU), staged 3 tiles ahead, 4 gld16/tile/thread.
// Per phase: 8 ds_read -> issue stage t+3 -> 16 MFMA -> vmcnt(8) -> barrier.
// vmcnt(8): tile t+1 landed, t+2/t+3 (8 loads) stay in flight ACROSS the barrier.
// Stage target buf[(t+3)&3] == buf[(t-1)&3]: its readers retired at the end-of-(t-1)
// barrier, which all waves passed before any phase-t stage issues. Ladder 8/4/0 drains.

// ---------------- MFMA GEMM 1 (ring-4): h1 = gelu(x_sel @ w1 + b1) ----------------
__global__ __launch_bounds__(256, 2) void ffn1_ring_kernel(const unsigned short* __restrict__ A,
                                                           const unsigned short* __restrict__ Bt,
                                                           const float* __restrict__ b1,
                                                           unsigned short* __restrict__ h1) {
    constexpr int K  = D_;        // 1024
    constexpr int NT = K / 32;    // 32 K-tiles
    __shared__ __align__(16) unsigned short smem[32768];   // 64 KiB: 4 x (A 4096 | B 4096 shorts)

    const int t    = threadIdx.x;
    const int lane = t & 63;
    const int wid  = t >> 6;
    const int quad = lane >> 4;
    const int lr   = lane & 15;
    const int wr   = wid >> 1;            // 0..1  (M)
    const int wc   = wid & 1;             // 0..1  (N)
    const int row0 = blockIdx.x * 128;
    const int col0 = blockIdx.y * 128;

    // staging: A region = 512 chunks (128 rows x 4), B same; thread t -> chunks t, t+256
    const char* aS[2]; const char* bS[2]; int oA[2], oB[2];
    #pragma unroll
    for (int j = 0; j < 2; ++j) {
        int s = t + j * 256;
        int rp = s >> 3, w = (s & 7) ^ (rp & 7);
        int gr = rp * 2 + (w >> 2), gc = w & 3;
        aS[j] = (const char*)A  + ((size_t)(row0 + gr) * K + (size_t)gc * 8) * 2;
        bS[j] = (const char*)Bt + ((size_t)(col0 + gr) * K + (size_t)gc * 8) * 2;
        oA[j] = s * 8;
        oB[j] = 4096 + s * 8;
    }

    // fragment bases (swizzled); mi/ni advance 16 rows = +512 shorts
    const int rbA = wr * 64 + lr, rA2 = rbA >> 1;
    const int aoff = (rA2 * 8 + ((((rbA & 1) << 2) | quad) ^ (rA2 & 7))) * 8;
    const int rbB = wc * 64 + lr, rB2 = rbB >> 1;
    const int boff = 4096 + (rB2 * 8 + ((((rbB & 1) << 2) | quad) ^ (rB2 & 7))) * 8;

    // ---- prologue: stage K-tiles 0,1,2 into ring bufs 0,1,2 ----
    #pragma unroll
    for (int pt = 0; pt < 3; ++pt) {
        unsigned short* buf = smem + pt * 8192;
        #pragma unroll
        for (int j = 0; j < 2; ++j) { gld16(aS[j], buf + oA[j]); gld16(bS[j], buf + oB[j]); }
        #pragma unroll
        for (int j = 0; j < 2; ++j) { aS[j] += 64; bS[j] += 64; }
    }
    asm volatile("s_waitcnt vmcnt(8)" ::: "memory");   // tile 0 landed; 1,2 in flight
    __builtin_amdgcn_s_barrier();

    float4v acc[4][4] = {};

    #pragma unroll 4
    for (int kt = 0; kt < NT; ++kt) {
        const unsigned short* cur = smem + (kt & 3) * 8192;
        unsigned short* nxt = smem + ((kt + 3) & 3) * 8192;
        short8 af[4], bq[4];
        #pragma unroll
        for (int mi = 0; mi < 4; ++mi) af[mi] = *(const short8*)(cur + aoff + mi * 512);
        #pragma unroll
        for (int ni = 0; ni < 4; ++ni) bq[ni] = *(const short8*)(cur + boff + ni * 512);
        if (kt + 3 < NT) {
            #pragma unroll
            for (int j = 0; j < 2; ++j) { gld16(aS[j], nxt + oA[j]); gld16(bS[j], nxt + oB[j]); }
            #pragma unroll
            for (int j = 0; j < 2; ++j) { aS[j] += 64; bS[j] += 64; }
        }
        __builtin_amdgcn_sched_barrier(0);
        __builtin_amdgcn_s_setprio(1);
        #pragma unroll
        for (int mi = 0; mi < 4; ++mi)
            #pragma unroll
            for (int ni = 0; ni < 4; ++ni)
                acc[mi][ni] = __builtin_amdgcn_mfma_f32_16x16x32_bf16(af[mi], bq[ni], acc[mi][ni], 0, 0, 0);
        __builtin_amdgcn_s_setprio(0);
        // counted wait: tile kt+1 landed; kt+2,kt+3 (8 loads) remain in flight
        if (kt < NT - 3)       asm volatile("s_waitcnt vmcnt(8)" ::: "memory");
        else if (kt == NT - 3) asm volatile("s_waitcnt vmcnt(4)" ::: "memory");
        else                   asm volatile("s_waitcnt vmcnt(0)" ::: "memory");
        __builtin_amdgcn_s_barrier();
    }

    // ---- epilogue: bias+GELU -> bf16 via per-wave LDS (16 rows x 66 shorts), full-128B-line stores ----
    float bias[4];
    #pragma unroll
    for (int ni = 0; ni < 4; ++ni) bias[ni] = b1[col0 + wc * 64 + ni * 16 + lr];
    unsigned short* ws_ = smem + wid * 1056;   // 4 waves x 1056 shorts
    const int co = col0 + wc * 64;
    #pragma unroll
    for (int mi = 0; mi < 4; ++mi) {
        const int ro = row0 + wr * 64 + mi * 16;
        #pragma unroll
        for (int ni = 0; ni < 4; ++ni)
            #pragma unroll
            for (int r = 0; r < 4; ++r) {
                float u = acc[mi][ni][r] + bias[ni];
                float tt = 1.5957691216057308f * u * (1.0f + 0.044715f * u * u);
                float g = u / (1.0f + __expf(-tt));
                ws_[(quad * 4 + r) * 66 + ni * 16 + lr] = f2bf(g);
            }
        asm volatile("s_waitcnt lgkmcnt(0)" ::: "memory");
        #pragma unroll
        for (int j = 0; j < 2; ++j) {
            int chk = lane + j * 64;          // 128 chunks = 16 rows x 8 x 16B
            int rr = chk >> 3, cc = chk & 7;
            *(short8*)(h1 + (size_t)(ro + rr) * DFF_ + co + cc * 8) =
                *(const short8*)(ws_ + rr * 66 + cc * 8);
        }
        asm volatile("s_waitcnt lgkmcnt(0)" ::: "memory");
    }
}

// ---------------- MFMA GEMM 2 (ring-4): out[sel] = x_sel + h1 @ w2 + b2 ----------------
__global__ __launch_bounds__(256, 2) void ffn2_ring_kernel(const unsigned short* __restrict__ A,
                                                           const unsigned short* __restrict__ Bt,
                                                           const float* __restrict__ b2,
                                                           const float* __restrict__ x,
                                                           const int* __restrict__ topk,
                                                           float* __restrict__ out) {
    constexpr int K  = DFF_;      // 4096
    constexpr int NT = K / 32;    // 128 K-tiles
    __shared__ __align__(16) unsigned short smem[32768];   // 64 KiB ring-4

    const int t    = threadIdx.x;
    const int lane = t & 63;
    const int wid  = t >> 6;
    const int quad = lane >> 4;
    const int lr   = lane & 15;
    const int wr   = wid >> 1;            // 0..1  (M)
    const int wc   = wid & 1;             // 0..1  (N)
    const int row0 = blockIdx.x * 128;
    const int col0 = blockIdx.y * 128;

    const char* aS[2]; const char* bS[2]; int oA[2], oB[2];
    #pragma unroll
    for (int j = 0; j < 2; ++j) {
        int s = t + j * 256;
        int rp = s >> 3, w = (s & 7) ^ (rp & 7);
        int gr = rp * 2 + (w >> 2), gc = w & 3;
        aS[j] = (const char*)A  + ((size_t)(row0 + gr) * K + (size_t)gc * 8) * 2;
        bS[j] = (const char*)Bt + ((size_t)(col0 + gr) * K + (size_t)gc * 8) * 2;
        oA[j] = s * 8;
        oB[j] = 4096 + s * 8;
    }

    const int rbA = wr * 64 + lr, rA2 = rbA >> 1;
    const int aoff = (rA2 * 8 + ((((rbA & 1) << 2) | quad) ^ (rA2 & 7))) * 8;
    const int rbB = wc * 64 + lr, rB2 = rbB >> 1;
    const int boff = 4096 + (rB2 * 8 + ((((rbB & 1) << 2) | quad) ^ (rB2 & 7))) * 8;

    // ---- prologue: stage K-tiles 0,1,2 ----
    #pragma unroll
    for (int pt = 0; pt < 3; ++pt) {
        unsigned short* buf = smem + pt * 8192;
        #pragma unroll
        for (int j = 0; j < 2; ++j) { gld16(aS[j], buf + oA[j]); gld16(bS[j], buf + oB[j]); }
        #pragma unroll
        for (int j = 0; j < 2; ++j) { aS[j] += 64; bS[j] += 64; }
    }
    asm volatile("s_waitcnt vmcnt(8)" ::: "memory");
    __builtin_amdgcn_s_barrier();

    float4v acc[4][4] = {};

    #pragma unroll 4
    for (int kt = 0; kt < NT; ++kt) {
        const unsigned short* cur = smem + (kt & 3) * 8192;
        unsigned short* nxt = smem + ((kt + 3) & 3) * 8192;
        short8 af[4], bq[4];
        #pragma unroll
        for (int mi = 0; mi < 4; ++mi) af[mi] = *(const short8*)(cur + aoff + mi * 512);
        #pragma unroll
        for (int ni = 0; ni < 4; ++ni) bq[ni] = *(const short8*)(cur + boff + ni * 512);
        if (kt + 3 < NT) {
            #pragma unroll
            for (int j = 0; j < 2; ++j) { gld16(aS[j], nxt + oA[j]); gld16(bS[j], nxt + oB[j]); }
            #pragma unroll
            for (int j = 0; j < 2; ++j) { aS[j] += 64; bS[j] += 64; }
        }
        __builtin_amdgcn_sched_barrier(0);
        __builtin_amdgcn_s_setprio(1);
        #pragma unroll
        for (int mi = 0; mi < 4; ++mi)
            #pragma unroll
            for (int ni = 0; ni < 4; ++ni)
                acc[mi][ni] = __builtin_amdgcn_mfma_f32_16x16x32_bf16(af[mi], bq[ni], acc[mi][ni], 0, 0, 0);
        __builtin_amdgcn_s_setprio(0);
        if (kt < NT - 3)       asm volatile("s_waitcnt vmcnt(8)" ::: "memory");
        else if (kt == NT - 3) asm volatile("s_waitcnt vmcnt(4)" ::: "memory");
        else                   asm volatile("s_waitcnt vmcnt(0)" ::: "memory");
        __builtin_amdgcn_s_barrier();
    }

    // ---- epilogue: scattered residual stores (identical math/order to r4 ffn2) ----
    #pragma unroll
    for (int mi = 0; mi < 4; ++mi) {
        #pragma unroll
        for (int r = 0; r < 4; ++r) {
            int row = row0 + wr * 64 + mi * 16 + quad * 4 + r;
            int gb = row >> 11;
            int tok = topk[row];
            size_t base = ((size_t)(gb * N_ + tok)) * D_;
            #pragma unroll
            for (int ni = 0; ni < 4; ++ni) {
                int col = col0 + wc * 64 + ni * 16 + lr;
                out[base + col] = x[base + col] + acc[mi][ni][r] + b2[col];
            }
        }
    }
}

extern "C" void kernel_launch(void* const* d_in, const int* in_sizes, int n_in,
                              void* d_out, int out_size, void* d_ws, size_t ws_size,
                              hipStream_t stream) {
    const float* x      = (const float*)d_in[0];
    const float* gate_w = (const float*)d_in[1];
    const float* w1     = (const float*)d_in[2];
    const float* b1     = (const float*)d_in[3];
    const float* w2     = (const float*)d_in[4];
    const float* b2     = (const float*)d_in[5];
    float* out = (float*)d_out;

    char* ws = (char*)d_ws;
    float*          scores = (float*)ws;                                        // 64 KiB
    int*            topk   = (int*)(ws + (64 << 10));                           // 32 KiB
    int*            slot   = (int*)(ws + (96 << 10));                           // 64 KiB
    unsigned short* xsel   = (unsigned short*)(ws + (160 << 10));               // 16 MiB
    unsigned short* w1t    = (unsigned short*)(ws + (160 << 10) + (16 << 20));  // 8 MiB  [4096][1024]
    unsigned short* w2t    = (unsigned short*)(ws + (160 << 10) + (24 << 20));  // 8 MiB  [1024][4096]
    unsigned short* h1     = (unsigned short*)(ws + (160 << 10) + (32 << 20));  // 64 MiB [8192][4096]

    scores_kernel<<<(B_ * N_) / 4, 256, 0, stream>>>(x, gate_w, scores, slot);
    select_topk_kernel<<<B_, 1024, 0, stream>>>(scores, topk, slot);

    transpose_both_kernel<<<8192, 256, 0, stream>>>(w1, w2, w1t, w2t);

    gather_copy_kernel<<<B_ * N_, 256, 0, stream>>>(x, slot, xsel, out);

    ffn1_ring_kernel<<<dim3(64, 32), 256, 0, stream>>>(xsel, w1t, b1, h1);
    ffn2_ring_kernel<<<dim3(64, 8), 256, 0, stream>>>(h1, w2t, b2, x, topk, out);
}

// Round 7
// 328.488 us; speedup vs baseline: 1.0406x; 1.0406x over previous
//
#include <hip/hip_runtime.h>
#include <math.h>

#define B_   4
#define N_   4096
#define D_   1024
#define DFF_ 4096
#define K_   2048

typedef __attribute__((ext_vector_type(8))) short short8;
typedef __attribute__((ext_vector_type(4))) float float4v;

__device__ __forceinline__ unsigned short f2bf(float f) {
    unsigned int u = __float_as_uint(f);
    u = (u + 0x7fffu + ((u >> 16) & 1u)) >> 16;   // RNE
    return (unsigned short)u;
}

__device__ __forceinline__ void gld16(const void* g, void* l) {
    __builtin_amdgcn_global_load_lds((const __attribute__((address_space(1))) void*)g,
                                     (__attribute__((address_space(3))) void*)l, 16, 0, 0);
}

// ---------------- scores (bit-identical selection math) + slot clear ----------------
__global__ __launch_bounds__(256) void scores_kernel(const float* __restrict__ x,
                                                     const float* __restrict__ gate_w,
                                                     float* __restrict__ scores,
                                                     int* __restrict__ slot) {
    int wave = (blockIdx.x * blockDim.x + threadIdx.x) >> 6;
    int lane = threadIdx.x & 63;
    if (wave >= B_ * N_) return;
    if (lane == 1) slot[wave] = -1;
    const float4* xr = (const float4*)(x + (size_t)wave * D_);
    const float4* g  = (const float4*)gate_w;
    float acc = 0.f;
    #pragma unroll
    for (int j = 0; j < D_ / 4 / 64; ++j) {
        float4 a = xr[lane + j * 64];
        float4 b = g[lane + j * 64];
        acc += a.x * b.x + a.y * b.y + a.z * b.z + a.w * b.w;
    }
    #pragma unroll
    for (int off = 32; off > 0; off >>= 1) acc += __shfl_down(acc, off, 64);
    if (lane == 0) scores[wave] = acc;
}

// ---------------- top-k radix select, wave-level scans; writes topk + global slot map ----------------
__global__ __launch_bounds__(1024) void select_topk_kernel(const float* __restrict__ scores,
                                                           int* __restrict__ topk,
                                                           int* __restrict__ slot) {
    __shared__ unsigned key[N_];
    __shared__ unsigned hist[256];
    __shared__ int sh_bin, sh_rem, sh_ngt;
    __shared__ int wsum[16], woff[16];
    int b = blockIdx.x, tid = threadIdx.x;
    int lane = tid & 63, wid = tid >> 6;

    for (int i = tid; i < N_; i += 1024) {
        unsigned u = __float_as_uint(scores[b * N_ + i]);
        key[i] = (u & 0x80000000u) ? ~u : (u | 0x80000000u);   // monotonic map
    }
    if (tid == 0) sh_ngt = 0;
    __syncthreads();

    unsigned prefix = 0, pmask = 0;
    int rem = K_;
    for (int shift = 24; shift >= 0; shift -= 8) {
        if (tid < 256) hist[tid] = 0;
        __syncthreads();
        for (int i = tid; i < N_; i += 1024) {
            unsigned k = key[i];
            if ((k & pmask) == prefix) atomicAdd(&hist[(k >> shift) & 255u], 1u);
        }
        __syncthreads();
        if (tid < 64) {   // wave 0: suffix scan of 256 bins, 4 bins/lane
            unsigned v0 = hist[4 * lane], v1 = hist[4 * lane + 1];
            unsigned v2 = hist[4 * lane + 2], v3 = hist[4 * lane + 3];
            unsigned s3 = v3, s2 = v2 + s3, s1 = v1 + s2, s0 = v0 + s1;
            unsigned t = s0;
            #pragma unroll
            for (int off = 1; off < 64; off <<= 1) {
                unsigned u = __shfl_down(t, off, 64);
                if (lane + off < 64) t += u;
            }
            unsigned above = t - s0;                  // keys in bins > 4*lane+3
            unsigned S0 = s0 + above, S1 = s1 + above, S2 = s2 + above, S3 = s3 + above;
            unsigned R = (unsigned)rem;
            if (S0 >= R && S1 < R) { sh_bin = 4 * lane;     sh_rem = rem - (int)S1; }
            if (S1 >= R && S2 < R) { sh_bin = 4 * lane + 1; sh_rem = rem - (int)S2; }
            if (S2 >= R && S3 < R) { sh_bin = 4 * lane + 2; sh_rem = rem - (int)S3; }
            if (S3 >= R && above < R) { sh_bin = 4 * lane + 3; sh_rem = rem - (int)above; }
        }
        __syncthreads();
        prefix |= ((unsigned)sh_bin) << shift;
        pmask  |= 0xffu << shift;
        rem = sh_rem;
    }
    unsigned T = prefix;          // exact key of k-th largest
    int c_gt = K_ - rem;          // count strictly greater

    // strictly-greater: ballot-compacted, arbitrary order, slots [0, c_gt)
    for (int i = tid; i < N_; i += 1024) {
        bool p = key[i] > T;
        unsigned long long m = __ballot(p);
        int cnt = __popcll(m);
        int basepos = 0;
        if (lane == 0 && cnt) basepos = atomicAdd(&sh_ngt, cnt);
        basepos = __shfl(basepos, 0, 64);
        if (p) {
            int pos = basepos + __popcll(m & ((1ULL << lane) - 1ULL));
            topk[b * K_ + pos] = i;
            slot[b * N_ + i] = b * K_ + pos;
        }
    }
    // ties: first `rem` by index -> slots [c_gt, K)
    int base = tid * 4, c = 0;
    #pragma unroll
    for (int j = 0; j < 4; ++j) c += (key[base + j] == T);
    int sc = c;
    #pragma unroll
    for (int off = 1; off < 64; off <<= 1) {
        int u = __shfl_up(sc, off, 64);
        if (lane >= off) sc += u;
    }
    if (lane == 63) wsum[wid] = sc;
    __syncthreads();
    if (tid == 0) {
        int run = 0;
        #pragma unroll
        for (int j = 0; j < 16; ++j) { woff[j] = run; run += wsum[j]; }
    }
    __syncthreads();
    int r = woff[wid] + sc - c;   // exclusive prefix among ties
    #pragma unroll
    for (int j = 0; j < 4; ++j) {
        if (key[base + j] == T) {
            if (r < rem) {
                topk[b * K_ + c_gt + r] = base + j;
                slot[b * N_ + base + j] = b * K_ + c_gt + r;
            }
            ++r;
        }
    }
}

// ---------------- fused: selected rows -> bf16 xsel[slot]; unselected -> out copy ----------------
__global__ __launch_bounds__(256) void gather_copy_kernel(const float* __restrict__ x,
                                                          const int* __restrict__ slot,
                                                          unsigned short* __restrict__ xsel,
                                                          float* __restrict__ out) {
    int row = blockIdx.x;
    int t = threadIdx.x;
    int s = slot[row];
    float4 v = ((const float4*)(x + (size_t)row * D_))[t];
    if (s >= 0) {
        ushort4 o;
        o.x = f2bf(v.x); o.y = f2bf(v.y); o.z = f2bf(v.z); o.w = f2bf(v.w);
        ((ushort4*)(xsel + (size_t)s * D_))[t] = o;
    } else {
        ((float4*)(out + (size_t)row * D_))[t] = v;
    }
}

// ---------------- both weight transposes (fp32 [R][C] -> bf16 [C][R]) in one launch ----------------
__global__ __launch_bounds__(256) void transpose_both_kernel(const float* __restrict__ w1,
                                                             const float* __restrict__ w2,
                                                             unsigned short* __restrict__ w1t,
                                                             unsigned short* __restrict__ w2t) {
    __shared__ float tile[32][33];
    int bid = blockIdx.x;
    const float* src; unsigned short* dst; int R, C, bx, by;
    if (bid < 4096) { src = w1; dst = w1t; R = D_;   C = DFF_; bx = bid & 127;          by = bid >> 7; }
    else            { src = w2; dst = w2t; R = DFF_; C = D_;   bx = (bid - 4096) & 31;  by = (bid - 4096) >> 5; }
    int tx = threadIdx.x & 31, ty = threadIdx.x >> 5;   // 32 x 8
    int c = bx * 32 + tx, r0 = by * 32;
    #pragma unroll
    for (int j = ty; j < 32; j += 8) tile[j][tx] = src[(size_t)(r0 + j) * C + c];
    __syncthreads();
    int dc = by * 32 + tx, dr0 = bx * 32;
    #pragma unroll
    for (int j = ty; j < 32; j += 8) dst[(size_t)(dr0 + j) * R + dc] = f2bf(tile[tx][j]);
}

// ======== ffn1: 256x256 8-phase fine-interleaved pipeline (m201 port) ========
// 512 thr (8 waves 2Mx4N), wave tile 128x64 SPLIT across halves:
//   rows: (mi>>2)*128 + wr*64 + (mi&3)*16 ; cols: (ni>>1)*128 + wc*32 + (ni&1)*16
// BK=64, double-buffer 2x64 KiB. Staging in 16 KiB half-tile units (2 gld16/thread):
//   phases read (h0,g0)(h1,g0)(h1,g1)(h0,g1); stages P1:SA0(t+1) P2:SB1(t+1)
//   P3:SB0(t+2) P4:SA1(t+2) -- each after its region's last-reader barrier.
// vmcnt(4) once per K-tile (2 younger units allowed in flight), never 0 in loop.
// BK=64 row-sweep swizzle (verified r4): chunk (r,c) at slot r*8 + (c^(r&7)).
__global__ __launch_bounds__(512, 2) void ffn1_8ph_kernel(const unsigned short* __restrict__ A,
                                                          const unsigned short* __restrict__ Bt,
                                                          const float* __restrict__ b1,
                                                          unsigned short* __restrict__ h1) {
    constexpr int K  = D_;        // 1024
    constexpr int NT = K / 64;    // 16 K-tiles
    __shared__ __align__(16) unsigned short smem[65536];   // 128 KiB: 2 x (A 32KB | B 32KB)

    const int t    = threadIdx.x;          // 0..511
    const int lane = t & 63;
    const int wid  = t >> 6;               // 0..7
    const int quad = lane >> 4;
    const int lr   = lane & 15;
    const int wr   = wid >> 2;             // 0..1 (M)
    const int wc   = wid & 3;              // 0..3 (N)
    const int row0 = blockIdx.x * 256;
    const int col0 = blockIdx.y * 256;

    // staging pointers: 4 units (A-h, B-h) x 2 loads; s = t + j*512, r=s>>3, c=(s&7)^(r&7)
    const char* pA[2][2]; const char* pB[2][2];
    int oA[2][2], oB[2][2];
    #pragma unroll
    for (int h = 0; h < 2; ++h)
        #pragma unroll
        for (int j = 0; j < 2; ++j) {
            int s = t + j * 512;
            int r = s >> 3, c = (s & 7) ^ (r & 7);
            pA[h][j] = (const char*)A  + ((size_t)(row0 + h * 128 + r) * K + (size_t)c * 8) * 2;
            pB[h][j] = (const char*)Bt + ((size_t)(col0 + h * 128 + r) * K + (size_t)c * 8) * 2;
            oA[h][j] = (h * 1024 + s) * 8;
            oB[h][j] = 16384 + (h * 1024 + s) * 8;
        }

    auto stageA = [&](int h, unsigned short* buf) {
        gld16(pA[h][0], buf + oA[h][0]); gld16(pA[h][1], buf + oA[h][1]);
        pA[h][0] += 128; pA[h][1] += 128;
    };
    auto stageB = [&](int h, unsigned short* buf) {
        gld16(pB[h][0], buf + oB[h][0]); gld16(pB[h][1], buf + oB[h][1]);
        pB[h][0] += 128; pB[h][1] += 128;
    };

    // fragment addressing (swizzled): row&7 == lr&7 for all frags
    int axor[2];
    #pragma unroll
    for (int kk = 0; kk < 2; ++kk) axor[kk] = ((kk * 4 + quad) ^ (lr & 7)) * 8;
    const int aBase = (wr * 64 + lr) * 64;           // +h*8192, +mi*1024
    const int bBase = 16384 + (wc * 32 + lr) * 64;   // +g*8192, +nj*1024

    unsigned short* sm0 = smem;
    unsigned short* sm1 = smem + 32768;

    // ---- prologue: tile 0 complete (8 loads) + tile 1's SB0,SA1 (4 loads) ----
    stageA(0, sm0); stageA(1, sm0); stageB(0, sm0); stageB(1, sm0);
    stageB(0, sm1); stageA(1, sm1);
    asm volatile("s_waitcnt vmcnt(4)" ::: "memory");   // tile 0 landed; SB0(1),SA1(1) in flight
    __builtin_amdgcn_s_barrier();

    float4v acc[8][4] = {};

    for (int kt = 0; kt < NT; ++kt) {
        unsigned short* cur = smem + (kt & 1) * 32768;
        unsigned short* nxt = smem + (((kt & 1) ^ 1)) * 32768;
        short8 afl[4][2], afh[4][2], bq0[2][2], bq1[2][2];

        // ---- P1: read A-low + B-g0; stage SA0(kt+1) ----
        #pragma unroll
        for (int mi = 0; mi < 4; ++mi)
            #pragma unroll
            for (int kk = 0; kk < 2; ++kk)
                afl[mi][kk] = *(const short8*)(cur + aBase + mi * 1024 + axor[kk]);
        #pragma unroll
        for (int nj = 0; nj < 2; ++nj)
            #pragma unroll
            for (int kk = 0; kk < 2; ++kk)
                bq0[nj][kk] = *(const short8*)(cur + bBase + nj * 1024 + axor[kk]);
        if (kt + 1 < NT) stageA(0, nxt);
        __builtin_amdgcn_sched_barrier(0);
        __builtin_amdgcn_s_barrier();
        __builtin_amdgcn_s_setprio(1);
        #pragma unroll
        for (int mi = 0; mi < 4; ++mi)
            #pragma unroll
            for (int nj = 0; nj < 2; ++nj)
                #pragma unroll
                for (int kk = 0; kk < 2; ++kk)
                    acc[mi][nj] = __builtin_amdgcn_mfma_f32_16x16x32_bf16(afl[mi][kk], bq0[nj][kk], acc[mi][nj], 0, 0, 0);
        __builtin_amdgcn_s_setprio(0);
        __builtin_amdgcn_s_barrier();

        // ---- P2: read A-high (B-g0 reused); stage SB1(kt+1) ----
        #pragma unroll
        for (int mi = 0; mi < 4; ++mi)
            #pragma unroll
            for (int kk = 0; kk < 2; ++kk)
                afh[mi][kk] = *(const short8*)(cur + aBase + 8192 + mi * 1024 + axor[kk]);
        if (kt + 1 < NT) stageB(1, nxt);
        __builtin_amdgcn_sched_barrier(0);
        __builtin_amdgcn_s_barrier();
        __builtin_amdgcn_s_setprio(1);
        #pragma unroll
        for (int mi = 0; mi < 4; ++mi)
            #pragma unroll
            for (int nj = 0; nj < 2; ++nj)
                #pragma unroll
                for (int kk = 0; kk < 2; ++kk)
                    acc[4 + mi][nj] = __builtin_amdgcn_mfma_f32_16x16x32_bf16(afh[mi][kk], bq0[nj][kk], acc[4 + mi][nj], 0, 0, 0);
        __builtin_amdgcn_s_setprio(0);
        __builtin_amdgcn_s_barrier();

        // ---- P3: read B-g1 (A-high reused); stage SB0(kt+2) into cur (SB0 freed at P2 barrier) ----
        #pragma unroll
        for (int nj = 0; nj < 2; ++nj)
            #pragma unroll
            for (int kk = 0; kk < 2; ++kk)
                bq1[nj][kk] = *(const short8*)(cur + bBase + 8192 + nj * 1024 + axor[kk]);
        if (kt + 2 < NT) stageB(0, cur);
        __builtin_amdgcn_sched_barrier(0);
        __builtin_amdgcn_s_barrier();
        __builtin_amdgcn_s_setprio(1);
        #pragma unroll
        for (int mi = 0; mi < 4; ++mi)
            #pragma unroll
            for (int nj = 0; nj < 2; ++nj)
                #pragma unroll
                for (int kk = 0; kk < 2; ++kk)
                    acc[4 + mi][2 + nj] = __builtin_amdgcn_mfma_f32_16x16x32_bf16(afh[mi][kk], bq1[nj][kk], acc[4 + mi][2 + nj], 0, 0, 0);
        __builtin_amdgcn_s_setprio(0);
        __builtin_amdgcn_s_barrier();

        // ---- P4: re-read A-low (B-g1 reused); stage SA1(kt+2) into cur (SA1 freed at P2 barrier) ----
        #pragma unroll
        for (int mi = 0; mi < 4; ++mi)
            #pragma unroll
            for (int kk = 0; kk < 2; ++kk)
                afl[mi][kk] = *(const short8*)(cur + aBase + mi * 1024 + axor[kk]);
        if (kt + 2 < NT) stageA(1, cur);
        __builtin_amdgcn_sched_barrier(0);
        __builtin_amdgcn_s_barrier();
        __builtin_amdgcn_s_setprio(1);
        #pragma unroll
        for (int mi = 0; mi < 4; ++mi)
            #pragma unroll
            for (int nj = 0; nj < 2; ++nj)
                #pragma unroll
                for (int kk = 0; kk < 2; ++kk)
                    acc[mi][2 + nj] = __builtin_amdgcn_mfma_f32_16x16x32_bf16(afl[mi][kk], bq1[nj][kk], acc[mi][2 + nj], 0, 0, 0);
        __builtin_amdgcn_s_setprio(0);
        // counted wait once per K-tile: everything issued through P2 (tile kt+1 complete) landed;
        // P3/P4 stages for kt+2 (4 loads) remain in flight across the barrier.
        if (kt < NT - 2)       asm volatile("s_waitcnt vmcnt(4)" ::: "memory");
        else if (kt == NT - 2) asm volatile("s_waitcnt vmcnt(0)" ::: "memory");
        __builtin_amdgcn_s_barrier();
    }

    // ---- epilogue: bias+GELU -> bf16 via per-wave LDS (16 rows x 40 shorts), 64B-line stores ----
    float bias[4];
    #pragma unroll
    for (int ni = 0; ni < 4; ++ni) bias[ni] = b1[col0 + (ni >> 1) * 128 + wc * 32 + (ni & 1) * 16 + lr];
    unsigned short* ws_ = smem + wid * 640;
    const int rr = lane >> 2, cc = lane & 3;
    #pragma unroll
    for (int mi = 0; mi < 8; ++mi) {
        const int ro = row0 + (mi >> 2) * 128 + wr * 64 + (mi & 3) * 16;
        #pragma unroll
        for (int g = 0; g < 2; ++g) {
            const int co = col0 + g * 128 + wc * 32;
            #pragma unroll
            for (int nj = 0; nj < 2; ++nj)
                #pragma unroll
                for (int r = 0; r < 4; ++r) {
                    float u = acc[mi][g * 2 + nj][r] + bias[g * 2 + nj];
                    float tt = 1.5957691216057308f * u * (1.0f + 0.044715f * u * u);
                    float gv = u / (1.0f + __expf(-tt));
                    ws_[(quad * 4 + r) * 40 + nj * 16 + lr] = f2bf(gv);
                }
            asm volatile("s_waitcnt lgkmcnt(0)" ::: "memory");
            *(short8*)(h1 + (size_t)(ro + rr) * DFF_ + co + cc * 8) =
                *(const short8*)(ws_ + rr * 40 + cc * 8);
            asm volatile("s_waitcnt lgkmcnt(0)" ::: "memory");
        }
    }
}

// ======== row-pair XOR swizzle (verified r2/r3: conflicts -> 0) for ffn2 ========
// Row = 32 shorts (4 x 16B chunks). Chunk (r,kc) at index (r>>1)*8 + ((((r&1)<<2)|kc) ^ ((r>>1)&7)).

// ---------------- MFMA GEMM 2 (r3-verified dbuf, 2 blocks/CU): out[sel] = x_sel + h1 @ w2 + b2 ----------------
__global__ __launch_bounds__(256, 2) void ffn2_db_kernel(const unsigned short* __restrict__ A,
                                                         const unsigned short* __restrict__ Bt,
                                                         const float* __restrict__ b2,
                                                         const float* __restrict__ x,
                                                         const int* __restrict__ topk,
                                                         float* __restrict__ out) {
    constexpr int K  = DFF_;      // 4096
    constexpr int NT = K / 32;    // 128 K-tiles
    __shared__ __align__(16) unsigned short smem[16384];   // 32 KiB: 2 x (A 4096 | B 4096 shorts)

    const int t    = threadIdx.x;
    const int lane = t & 63;
    const int wid  = t >> 6;
    const int quad = lane >> 4;
    const int lr   = lane & 15;
    const int wr   = wid >> 1;            // 0..1  (M)
    const int wc   = wid & 1;             // 0..1  (N)
    const int row0 = blockIdx.x * 128;
    const int col0 = blockIdx.y * 128;

    const int ch0 = t, ch1 = t + 256;
    const int rp0 = ch0 >> 3, w0 = (ch0 & 7) ^ (rp0 & 7);
    const int rp1 = ch1 >> 3, w1 = (ch1 & 7) ^ (rp1 & 7);
    const char* aS0 = (const char*)A  + ((size_t)(row0 + rp0 * 2 + (w0 >> 2)) * K + (size_t)(w0 & 3) * 8) * 2;
    const char* aS1 = (const char*)A  + ((size_t)(row0 + rp1 * 2 + (w1 >> 2)) * K + (size_t)(w1 & 3) * 8) * 2;
    const char* bS0 = (const char*)Bt + ((size_t)(col0 + rp0 * 2 + (w0 >> 2)) * K + (size_t)(w0 & 3) * 8) * 2;
    const char* bS1 = (const char*)Bt + ((size_t)(col0 + rp1 * 2 + (w1 >> 2)) * K + (size_t)(w1 & 3) * 8) * 2;
    const int oA0 = ch0 * 8, oA1 = ch1 * 8;
    const int oB0 = 4096 + ch0 * 8, oB1 = 4096 + ch1 * 8;

    const int rbA = wr * 64 + lr, rA2 = rbA >> 1;
    const int aoff = (rA2 * 8 + ((((rbA & 1) << 2) | quad) ^ (rA2 & 7))) * 8;
    const int rbB = wc * 64 + lr, rB2 = rbB >> 1;
    const int boff = 4096 + (rB2 * 8 + ((((rbB & 1) << 2) | quad) ^ (rB2 & 7))) * 8;

    unsigned short* lds0 = smem;
    unsigned short* lds1 = smem + 8192;

    gld16(aS0, lds0 + oA0); gld16(aS1, lds0 + oA1);
    gld16(bS0, lds0 + oB0); gld16(bS1, lds0 + oB1);
    aS0 += 64; aS1 += 64; bS0 += 64; bS1 += 64;
    asm volatile("s_waitcnt vmcnt(0)" ::: "memory");
    __builtin_amdgcn_s_barrier();

    float4v acc[4][4] = {};
    short8 af[4], bq[4];

    auto step = [&](const unsigned short* cur, unsigned short* nxt, bool pf) {
        #pragma unroll
        for (int mi = 0; mi < 4; ++mi) af[mi] = *(const short8*)(cur + aoff + mi * 512);
        #pragma unroll
        for (int ni = 0; ni < 4; ++ni) bq[ni] = *(const short8*)(cur + boff + ni * 512);
        if (pf) {
            gld16(aS0, nxt + oA0); gld16(aS1, nxt + oA1);
            gld16(bS0, nxt + oB0); gld16(bS1, nxt + oB1);
            aS0 += 64; aS1 += 64; bS0 += 64; bS1 += 64;
        }
        __builtin_amdgcn_sched_barrier(0);
        __builtin_amdgcn_s_setprio(1);
        #pragma unroll
        for (int mi = 0; mi < 4; ++mi)
            #pragma unroll
            for (int ni = 0; ni < 4; ++ni)
                acc[mi][ni] = __builtin_amdgcn_mfma_f32_16x16x32_bf16(af[mi], bq[ni], acc[mi][ni], 0, 0, 0);
        __builtin_amdgcn_s_setprio(0);
        asm volatile("s_waitcnt vmcnt(0)" ::: "memory");
        __builtin_amdgcn_s_barrier();
    };

    for (int kt = 0; kt < NT - 2; kt += 2) { step(lds0, lds1, true); step(lds1, lds0, true); }
    step(lds0, lds1, true);    // kt = NT-2
    step(lds1, lds0, false);   // kt = NT-1

    #pragma unroll
    for (int mi = 0; mi < 4; ++mi) {
        #pragma unroll
        for (int r = 0; r < 4; ++r) {
            int row = row0 + wr * 64 + mi * 16 + quad * 4 + r;
            int gb = row >> 11;
            int tok = topk[row];
            size_t base = ((size_t)(gb * N_ + tok)) * D_;
            #pragma unroll
            for (int ni = 0; ni < 4; ++ni) {
                int col = col0 + wc * 64 + ni * 16 + lr;
                out[base + col] = x[base + col] + acc[mi][ni][r] + b2[col];
            }
        }
    }
}

extern "C" void kernel_launch(void* const* d_in, const int* in_sizes, int n_in,
                              void* d_out, int out_size, void* d_ws, size_t ws_size,
                              hipStream_t stream) {
    const float* x      = (const float*)d_in[0];
    const float* gate_w = (const float*)d_in[1];
    const float* w1     = (const float*)d_in[2];
    const float* b1     = (const float*)d_in[3];
    const float* w2     = (const float*)d_in[4];
    const float* b2     = (const float*)d_in[5];
    float* out = (float*)d_out;

    char* ws = (char*)d_ws;
    float*          scores = (float*)ws;                                        // 64 KiB
    int*            topk   = (int*)(ws + (64 << 10));                           // 32 KiB
    int*            slot   = (int*)(ws + (96 << 10));                           // 64 KiB
    unsigned short* xsel   = (unsigned short*)(ws + (160 << 10));               // 16 MiB
    unsigned short* w1t    = (unsigned short*)(ws + (160 << 10) + (16 << 20));  // 8 MiB  [4096][1024]
    unsigned short* w2t    = (unsigned short*)(ws + (160 << 10) + (24 << 20));  // 8 MiB  [1024][4096]
    unsigned short* h1     = (unsigned short*)(ws + (160 << 10) + (32 << 20));  // 64 MiB [8192][4096]

    scores_kernel<<<(B_ * N_) / 4, 256, 0, stream>>>(x, gate_w, scores, slot);
    select_topk_kernel<<<B_, 1024, 0, stream>>>(scores, topk, slot);

    transpose_both_kernel<<<8192, 256, 0, stream>>>(w1, w2, w1t, w2t);

    gather_copy_kernel<<<B_ * N_, 256, 0, stream>>>(x, slot, xsel, out);

    ffn1_8ph_kernel<<<dim3(32, 16), 512, 0, stream>>>(xsel, w1t, b1, h1);
    ffn2_db_kernel<<<dim3(64, 8), 256, 0, stream>>>(h1, w2t, b2, x, topk, out);
}